// Round 1
// baseline (557.362 us; speedup 1.0000x reference)
//
#include <hip/hip_runtime.h>
#include <hip/hip_bf16.h>

typedef __attribute__((ext_vector_type(8))) __bf16 bf16x8;
typedef __attribute__((ext_vector_type(4))) float f32x4;

#define MFMA16(a, b, c) __builtin_amdgcn_mfma_f32_16x16x32_bf16((a), (b), (c), 0, 0, 0)

__device__ __forceinline__ unsigned short f2bf(float f) {
    unsigned u = __builtin_bit_cast(unsigned, f);
    u = (u + 0x7fffu + ((u >> 16) & 1u)) >> 16;
    return (unsigned short)u;
}

__device__ __forceinline__ void gll16(const void* g, void* l) {
    __builtin_amdgcn_global_load_lds((const __attribute__((address_space(1))) void*)g,
                                     (__attribute__((address_space(3))) void*)l, 16, 0, 0);
}

// ---------------- fp32 -> bf16 convert (vectorized, G13) ----------------
__global__ __launch_bounds__(256) void cvt_f32_bf16(const float4* __restrict__ in,
                                                    ushort4* __restrict__ out, int n4) {
    int i = blockIdx.x * 256 + threadIdx.x;
    if (i >= n4) return;
    float4 v = in[i];
    ushort4 o;
    o.x = f2bf(v.x); o.y = f2bf(v.y); o.z = f2bf(v.z); o.w = f2bf(v.w);
    out[i] = o;
}

// ---------------- RoPE cos/sin table: tbl[t*32+j] = (cos, sin) ----------------
__global__ __launch_bounds__(256) void trig_table(float2* __restrict__ tbl) {
    int i = blockIdx.x * 256 + threadIdx.x;   // 65536 = 2048*32
    int t = i >> 5, j = i & 31;
    float inv = powf(10000.0f, -(float)(2 * j) * (1.0f / 64.0f));
    float a = (float)t * inv;
    tbl[i] = make_float2(cosf(a), sinf(a));
}

// ---------------- GEMM: C(MxN) = A(MxK) @ Bt(NxK)^T, bf16 in, fp32 out ----------------
// m97 structure: 128x128 tile, BK=32, 4 waves each 64x64, global_load_lds w=16, dbuf LDS.
__global__ __launch_bounds__(256) void gemm_bt(const unsigned short* __restrict__ A,
                                               const unsigned short* __restrict__ Bt,
                                               float* __restrict__ C, int M, int N, int K) {
    __shared__ unsigned short As[2][128 * 32];
    __shared__ unsigned short Bs[2][128 * 32];
    const int tid = threadIdx.x;
    const int wid = tid >> 6, lane = tid & 63;
    const size_t brow = (size_t)blockIdx.x * 128, bcol = (size_t)blockIdx.y * 128;
    const int nkt = K >> 5;

    auto stage = [&](int buf, int kt) {
#pragma unroll
        for (int j = 0; j < 2; ++j) {
            int e = (j * 256 + tid) * 8;
            int r = e >> 5, c = e & 31;
            gll16(A + (brow + r) * K + kt * 32 + c, &As[buf][e]);
        }
#pragma unroll
        for (int j = 0; j < 2; ++j) {
            int e = (j * 256 + tid) * 8;
            int r = e >> 5, c = e & 31;
            gll16(Bt + (bcol + r) * K + kt * 32 + c, &Bs[buf][e]);
        }
    };

    f32x4 acc[4][4] = {};
    const int wm = (wid >> 1) * 64, wn = (wid & 1) * 64;
    const int fr = lane & 15, fk = (lane >> 4) * 8;

    stage(0, 0);
    for (int kt = 0; kt < nkt; ++kt) {
        __syncthreads();                 // drains vmcnt for stage(kt) + guards buffer reuse
        if (kt + 1 < nkt) stage((kt + 1) & 1, kt + 1);
        const int buf = kt & 1;
        bf16x8 af[4], bfr[4];
#pragma unroll
        for (int i = 0; i < 4; ++i)
            af[i] = *(const bf16x8*)&As[buf][(wm + i * 16 + fr) * 32 + fk];
#pragma unroll
        for (int i = 0; i < 4; ++i)
            bfr[i] = *(const bf16x8*)&Bs[buf][(wn + i * 16 + fr) * 32 + fk];
#pragma unroll
        for (int i = 0; i < 4; ++i)
#pragma unroll
            for (int j = 0; j < 4; ++j)
                acc[i][j] = MFMA16(af[i], bfr[j], acc[i][j]);
    }

    const int orow = (lane >> 4) * 4, ocol = lane & 15;
#pragma unroll
    for (int i = 0; i < 4; ++i)
#pragma unroll
        for (int j = 0; j < 4; ++j)
#pragma unroll
            for (int r = 0; r < 4; ++r)
                C[(brow + wm + i * 16 + orow + r) * N + (bcol + wn + j * 16 + ocol)] =
                    acc[i][j][r];
}

// ---------------- RoPE + QK-RMSNorm + layout split ----------------
// qkv: fp32 [8192][1536] (q 0..1023 | k 1024..1279 | v 1280..1535)
// qb: bf16 [B][H][T][D], kb: bf16 [B][KVH][T][D], vb: bf16 [B][KVH][T][D]
__global__ __launch_bounds__(256) void rope_norm(const float* __restrict__ qkv,
                                                 const float2* __restrict__ tbl,
                                                 unsigned short* __restrict__ qb,
                                                 unsigned short* __restrict__ kb,
                                                 unsigned short* __restrict__ vb) {
    int unit = blockIdx.x * 4 + (threadIdx.x >> 6);   // (row, head-slot), 8192*24 units
    int lane = threadIdx.x & 63;
    int row = unit / 24;
    int hh = unit - row * 24;
    int b = row >> 11, t = row & 2047;
    int col = (hh < 16) ? hh * 64 : (hh < 20 ? 1024 + (hh - 16) * 64 : 1280 + (hh - 20) * 64);
    float x = qkv[(size_t)row * 1536 + col + lane];
    float o = x;
    if (hh < 20) {
        float partner = __shfl_xor(x, 1);
        float2 cs = tbl[t * 32 + (lane >> 1)];
        float sgn = (lane & 1) ? cs.y : -cs.y;   // even: xe*c - xo*s ; odd: xe*s + xo*c
        o = x * cs.x + partner * sgn;
        float ss = o * o;
#pragma unroll
        for (int off = 1; off < 64; off <<= 1) ss += __shfl_xor(ss, off);
        o = o * rsqrtf(ss * (1.0f / 64.0f) + 1e-6f);
    }
    unsigned short ob = f2bf(o);
    if (hh < 16)
        qb[(((size_t)(b * 16 + hh)) * 2048 + t) * 64 + lane] = ob;
    else if (hh < 20)
        kb[(((size_t)(b * 4 + (hh - 16))) * 2048 + t) * 64 + lane] = ob;
    else
        vb[(((size_t)(b * 4 + (hh - 20))) * 2048 + t) * 64 + lane] = ob;
}

// ---------------- V transpose: [B*KVH][T][D] -> [B*KVH][D][T] ----------------
__global__ __launch_bounds__(256) void vtrans(const unsigned short* __restrict__ vb,
                                              unsigned short* __restrict__ vt) {
    __shared__ unsigned short tile[64][72];
    int bk = blockIdx.y, t0 = blockIdx.x * 64;
    int i = threadIdx.x >> 2, c0 = (threadIdx.x & 3) * 16;
    const unsigned short* src = vb + ((size_t)bk * 2048 + t0) * 64;
#pragma unroll
    for (int j = 0; j < 16; ++j) tile[i][c0 + j] = src[i * 64 + c0 + j];
    __syncthreads();
    unsigned short* dst = vt + (size_t)bk * 64 * 2048 + (size_t)i * 2048 + t0 + c0;
#pragma unroll
    for (int j = 0; j < 16; ++j) dst[j] = tile[c0 + j][i];
}

// ---------------- causal flash attention ----------------
// grid: (T/64, B*H), 4 waves/block, each wave owns a 16-row Q tile.
__global__ __launch_bounds__(256) void attn_fwd(const unsigned short* __restrict__ qb,
                                                const unsigned short* __restrict__ kbuf,
                                                const unsigned short* __restrict__ vt,
                                                unsigned short* __restrict__ y) {
    const float SCALE = 0.125f;
    int bh = blockIdx.y;
    int b = bh >> 4, h = bh & 15, kvh = h >> 2;
    int wid = threadIdx.x >> 6, lane = threadIdx.x & 63;
    int qrow0 = blockIdx.x * 64 + wid * 16;
    const unsigned short* Q = qb + ((size_t)(b * 16 + h)) * 2048 * 64;
    const unsigned short* Kp = kbuf + ((size_t)(b * 4 + kvh)) * 2048 * 64;
    const unsigned short* Vp = vt + ((size_t)(b * 4 + kvh)) * 64 * 2048;
    const int fr = lane & 15, fk8 = (lane >> 4) * 8, rbase = (lane >> 4) * 4;

    bf16x8 qf0 = *(const bf16x8*)&Q[(qrow0 + fr) * 64 + fk8];
    bf16x8 qf1 = *(const bf16x8*)&Q[(qrow0 + fr) * 64 + 32 + fk8];

    f32x4 accO[4] = {};
    float mrun[4], lrun[4];
#pragma unroll
    for (int r = 0; r < 4; ++r) { mrun[r] = -1e30f; lrun[r] = 0.0f; }

    __shared__ unsigned short sP[4][512];
    unsigned short* myP = sP[wid];

    int nkt = (qrow0 + 47) >> 5;    // 32-key tiles covering keys 0..qrow0+15
    for (int kt = 0; kt < nkt; ++kt) {
        int kb0 = kt * 32;
        // S = Q @ K^T   (two 16-key column tiles)
        f32x4 s0 = {}, s1 = {};
        {
            bf16x8 k00 = *(const bf16x8*)&Kp[(kb0 + fr) * 64 + fk8];
            bf16x8 k01 = *(const bf16x8*)&Kp[(kb0 + fr) * 64 + 32 + fk8];
            s0 = MFMA16(qf0, k00, s0);
            s0 = MFMA16(qf1, k01, s0);
            bf16x8 k10 = *(const bf16x8*)&Kp[(kb0 + 16 + fr) * 64 + fk8];
            bf16x8 k11 = *(const bf16x8*)&Kp[(kb0 + 16 + fr) * 64 + 32 + fk8];
            s1 = MFMA16(qf0, k10, s1);
            s1 = MFMA16(qf1, k11, s1);
        }
        // scale + causal mask; row-wise online softmax (16-lane shfl reduce)
        float sv0[4], sv1[4], mt[4];
#pragma unroll
        for (int r = 0; r < 4; ++r) {
            int row = qrow0 + rbase + r;
            float a = s0[r] * SCALE;
            if (kb0 + fr > row) a = -1e30f;
            float c = s1[r] * SCALE;
            if (kb0 + 16 + fr > row) c = -1e30f;
            sv0[r] = a; sv1[r] = c;
            mt[r] = fmaxf(a, c);
        }
#pragma unroll
        for (int off = 1; off < 16; off <<= 1)
#pragma unroll
            for (int r = 0; r < 4; ++r) mt[r] = fmaxf(mt[r], __shfl_xor(mt[r], off));

        float sf[4], psum[4];
#pragma unroll
        for (int r = 0; r < 4; ++r) {
            float mnew = fmaxf(mrun[r], mt[r]);
            sf[r] = __expf(mrun[r] - mnew);
            mrun[r] = mnew;
            float p0 = __expf(sv0[r] - mnew);
            float p1 = __expf(sv1[r] - mnew);
            psum[r] = p0 + p1;
            myP[(rbase + r) * 32 + fr] = f2bf(p0);
            myP[(rbase + r) * 32 + 16 + fr] = f2bf(p1);
        }
#pragma unroll
        for (int off = 1; off < 16; off <<= 1)
#pragma unroll
            for (int r = 0; r < 4; ++r) psum[r] += __shfl_xor(psum[r], off);
#pragma unroll
        for (int r = 0; r < 4; ++r) lrun[r] = lrun[r] * sf[r] + psum[r];
        // rescale O accumulator
#pragma unroll
        for (int nd = 0; nd < 4; ++nd)
#pragma unroll
            for (int r = 0; r < 4; ++r) accO[nd][r] *= sf[r];

        // P relayout via per-wave LDS round trip -> A-fragment
        asm volatile("s_waitcnt lgkmcnt(0)" ::: "memory");
        bf16x8 pf = *(const bf16x8*)&myP[fr * 32 + fk8];
        // O += P @ V   (V^T rows are contiguous over keys)
#pragma unroll
        for (int nd = 0; nd < 4; ++nd) {
            bf16x8 vf = *(const bf16x8*)&Vp[(nd * 16 + fr) * 2048 + kb0 + fk8];
            accO[nd] = MFMA16(pf, vf, accO[nd]);
        }
        asm volatile("" ::: "memory");   // keep next tile's sP writes after this read
    }

    // finalize: y[b][t][h*64+d] bf16
#pragma unroll
    for (int r = 0; r < 4; ++r) {
        float inv = 1.0f / lrun[r];
        size_t rowoff = ((size_t)b * 2048 + (qrow0 + rbase + r)) * 1024 + h * 64;
#pragma unroll
        for (int nd = 0; nd < 4; ++nd)
            y[rowoff + nd * 16 + fr] = f2bf(accO[nd][r] * inv);
    }
}

extern "C" void kernel_launch(void* const* d_in, const int* in_sizes, int n_in,
                              void* d_out, int out_size, void* d_ws, size_t ws_size,
                              hipStream_t stream) {
    const float* x = (const float*)d_in[0];
    const float* wq = (const float*)d_in[1];
    const float* wk = (const float*)d_in[2];
    const float* wv = (const float*)d_in[3];
    const float* wo = (const float*)d_in[4];
    float* out = (float*)d_out;

    char* ws = (char*)d_ws;
    size_t off = 0;
    auto alloc = [&](size_t bytes) {
        void* p = ws + off;
        off += (bytes + 255) & ~(size_t)255;
        return p;
    };
    // B=4 T=2048 C=1024 H=16 KVH=4 D=64 ; M = B*T = 8192
    unsigned short* xb    = (unsigned short*)alloc(8192ull * 1024 * 2);   // x bf16
    unsigned short* wqkvb = (unsigned short*)alloc(1536ull * 1024 * 2);   // [wq;wk;wv] bf16
    unsigned short* wob   = (unsigned short*)alloc(1024ull * 1024 * 2);   // wo bf16
    float*          qkv   = (float*)alloc(8192ull * 1536 * 4);            // fp32 QKV
    float2*         tbl   = (float2*)alloc(2048ull * 32 * 8);             // cos/sin
    unsigned short* qb    = (unsigned short*)alloc(8192ull * 1024 * 2);   // [B,H,T,D]
    unsigned short* kb    = (unsigned short*)alloc(4ull * 4 * 2048 * 64 * 2); // [B,KVH,T,D]
    unsigned short* vb    = (unsigned short*)alloc(4ull * 4 * 2048 * 64 * 2); // [B,KVH,T,D]
    unsigned short* vt    = (unsigned short*)alloc(4ull * 4 * 64 * 2048 * 2); // [B,KVH,D,T]
    unsigned short* ybf   = (unsigned short*)qkv;  // alias: qkv dead after rope_norm

    // 1) converts
    cvt_f32_bf16<<<(2097152 + 255) / 256, 256, 0, stream>>>((const float4*)x, (ushort4*)xb, 2097152);
    cvt_f32_bf16<<<(262144 + 255) / 256, 256, 0, stream>>>((const float4*)wq, (ushort4*)wqkvb, 262144);
    cvt_f32_bf16<<<(65536 + 255) / 256, 256, 0, stream>>>((const float4*)wk, (ushort4*)(wqkvb + 1048576), 65536);
    cvt_f32_bf16<<<(65536 + 255) / 256, 256, 0, stream>>>((const float4*)wv, (ushort4*)(wqkvb + 1310720), 65536);
    cvt_f32_bf16<<<(262144 + 255) / 256, 256, 0, stream>>>((const float4*)wo, (ushort4*)wob, 262144);

    // 2) trig table
    trig_table<<<256, 256, 0, stream>>>(tbl);

    // 3) QKV GEMM: [8192x1024] @ [1536x1024]^T -> fp32 [8192x1536]
    gemm_bt<<<dim3(64, 12), 256, 0, stream>>>(xb, wqkvb, qkv, 8192, 1536, 1024);

    // 4) RoPE + QK-norm + layout
    rope_norm<<<(8192 * 24) / 4, 256, 0, stream>>>(qkv, tbl, qb, kb, vb);

    // 5) V transpose
    vtrans<<<dim3(32, 16), 256, 0, stream>>>(vb, vt);

    // 6) flash attention -> ybf [8192 x 1024] bf16
    attn_fwd<<<dim3(32, 64), 256, 0, stream>>>(qb, kb, vt, ybf);

    // 7) output GEMM: [8192x1024] @ [1024x1024]^T -> d_out fp32
    gemm_bt<<<dim3(64, 8), 256, 0, stream>>>(ybf, wob, out, 8192, 1024, 1024);
}

// Round 2
// 341.847 us; speedup vs baseline: 1.6304x; 1.6304x over previous
//
#include <hip/hip_runtime.h>
#include <hip/hip_bf16.h>

typedef __attribute__((ext_vector_type(8))) __bf16 bf16x8;
typedef __attribute__((ext_vector_type(4))) float f32x4;

#define MFMA16(a, b, c) __builtin_amdgcn_mfma_f32_16x16x32_bf16((a), (b), (c), 0, 0, 0)

__device__ __forceinline__ unsigned short f2bf(float f) {
    unsigned u = __builtin_bit_cast(unsigned, f);
    u = (u + 0x7fffu + ((u >> 16) & 1u)) >> 16;
    return (unsigned short)u;
}

__device__ __forceinline__ void gll16(const void* g, void* l) {
    __builtin_amdgcn_global_load_lds((const __attribute__((address_space(1))) void*)g,
                                     (__attribute__((address_space(3))) void*)l, 16, 0, 0);
}

// ---------------- fp32 -> bf16 convert (vectorized, G13) ----------------
__global__ __launch_bounds__(256) void cvt_f32_bf16(const float4* __restrict__ in,
                                                    ushort4* __restrict__ out, int n4) {
    int i = blockIdx.x * 256 + threadIdx.x;
    if (i >= n4) return;
    float4 v = in[i];
    ushort4 o;
    o.x = f2bf(v.x); o.y = f2bf(v.y); o.z = f2bf(v.z); o.w = f2bf(v.w);
    out[i] = o;
}

// ---------------- RoPE cos/sin table: tbl[t*32+j] = (cos, sin) ----------------
__global__ __launch_bounds__(256) void trig_table(float2* __restrict__ tbl) {
    int i = blockIdx.x * 256 + threadIdx.x;   // 65536 = 2048*32
    int t = i >> 5, j = i & 31;
    float inv = powf(10000.0f, -(float)(2 * j) * (1.0f / 64.0f));
    float a = (float)t * inv;
    tbl[i] = make_float2(cosf(a), sinf(a));
}

// ---------------- GEMM: C(MxN) = A(MxK) @ Bt(NxK)^T, bf16 in, fp32 out ----------------
__global__ __launch_bounds__(256) void gemm_bt(const unsigned short* __restrict__ A,
                                               const unsigned short* __restrict__ Bt,
                                               float* __restrict__ C, int M, int N, int K) {
    __shared__ unsigned short As[2][128 * 32];
    __shared__ unsigned short Bs[2][128 * 32];
    const int tid = threadIdx.x;
    const int wid = tid >> 6, lane = tid & 63;
    const size_t brow = (size_t)blockIdx.x * 128, bcol = (size_t)blockIdx.y * 128;
    const int nkt = K >> 5;

    auto stage = [&](int buf, int kt) {
#pragma unroll
        for (int j = 0; j < 2; ++j) {
            int e = (j * 256 + tid) * 8;
            int r = e >> 5, c = e & 31;
            gll16(A + (brow + r) * K + kt * 32 + c, &As[buf][e]);
        }
#pragma unroll
        for (int j = 0; j < 2; ++j) {
            int e = (j * 256 + tid) * 8;
            int r = e >> 5, c = e & 31;
            gll16(Bt + (bcol + r) * K + kt * 32 + c, &Bs[buf][e]);
        }
    };

    f32x4 acc[4][4] = {};
    const int wm = (wid >> 1) * 64, wn = (wid & 1) * 64;
    const int fr = lane & 15, fk = (lane >> 4) * 8;

    stage(0, 0);
    for (int kt = 0; kt < nkt; ++kt) {
        __syncthreads();
        if (kt + 1 < nkt) stage((kt + 1) & 1, kt + 1);
        const int buf = kt & 1;
        bf16x8 af[4], bfr[4];
#pragma unroll
        for (int i = 0; i < 4; ++i)
            af[i] = *(const bf16x8*)&As[buf][(wm + i * 16 + fr) * 32 + fk];
#pragma unroll
        for (int i = 0; i < 4; ++i)
            bfr[i] = *(const bf16x8*)&Bs[buf][(wn + i * 16 + fr) * 32 + fk];
#pragma unroll
        for (int i = 0; i < 4; ++i)
#pragma unroll
            for (int j = 0; j < 4; ++j)
                acc[i][j] = MFMA16(af[i], bfr[j], acc[i][j]);
    }

    const int orow = (lane >> 4) * 4, ocol = lane & 15;
#pragma unroll
    for (int i = 0; i < 4; ++i)
#pragma unroll
        for (int j = 0; j < 4; ++j)
#pragma unroll
            for (int r = 0; r < 4; ++r)
                C[(brow + wm + i * 16 + orow + r) * N + (bcol + wn + j * 16 + ocol)] =
                    acc[i][j][r];
}

// ---------------- RoPE + QK-RMSNorm + layout split (q pre-scaled by 1/sqrt(D)) ----------------
__global__ __launch_bounds__(256) void rope_norm(const float* __restrict__ qkv,
                                                 const float2* __restrict__ tbl,
                                                 unsigned short* __restrict__ qb,
                                                 unsigned short* __restrict__ kb,
                                                 unsigned short* __restrict__ vb) {
    int unit = blockIdx.x * 4 + (threadIdx.x >> 6);
    int lane = threadIdx.x & 63;
    int row = unit / 24;
    int hh = unit - row * 24;
    int b = row >> 11, t = row & 2047;
    int col = (hh < 16) ? hh * 64 : (hh < 20 ? 1024 + (hh - 16) * 64 : 1280 + (hh - 20) * 64);
    float x = qkv[(size_t)row * 1536 + col + lane];
    float o = x;
    if (hh < 20) {
        float partner = __shfl_xor(x, 1);
        float2 cs = tbl[t * 32 + (lane >> 1)];
        float sgn = (lane & 1) ? cs.y : -cs.y;
        o = x * cs.x + partner * sgn;
        float ss = o * o;
#pragma unroll
        for (int off = 1; off < 64; off <<= 1) ss += __shfl_xor(ss, off);
        o = o * rsqrtf(ss * (1.0f / 64.0f) + 1e-6f);
        if (hh < 16) o *= 0.125f;   // fold attention scale 1/sqrt(64) into q
    }
    unsigned short ob = f2bf(o);
    if (hh < 16)
        qb[(((size_t)(b * 16 + hh)) * 2048 + t) * 64 + lane] = ob;
    else if (hh < 20)
        kb[(((size_t)(b * 4 + (hh - 16))) * 2048 + t) * 64 + lane] = ob;
    else
        vb[(((size_t)(b * 4 + (hh - 20))) * 2048 + t) * 64 + lane] = ob;
}

// ---------------- V transpose: [B*KVH][T][D] -> [B*KVH][D][T] ----------------
__global__ __launch_bounds__(256) void vtrans(const unsigned short* __restrict__ vb,
                                              unsigned short* __restrict__ vt) {
    __shared__ unsigned short tile[64][72];
    int bk = blockIdx.y, t0 = blockIdx.x * 64;
    int i = threadIdx.x >> 2, c0 = (threadIdx.x & 3) * 16;
    const unsigned short* src = vb + ((size_t)bk * 2048 + t0) * 64;
#pragma unroll
    for (int j = 0; j < 16; ++j) tile[i][c0 + j] = src[i * 64 + c0 + j];
    __syncthreads();
    unsigned short* dst = vt + (size_t)bk * 64 * 2048 + (size_t)i * 2048 + t0 + c0;
#pragma unroll
    for (int j = 0; j < 16; ++j) dst[j] = tile[c0 + j][i];
}

// ---------------- causal flash attention ----------------
// grid: (16, B*H), 4 waves/block, each wave owns 32 q rows; KVBLK=64.
// q-tiles launched heaviest-first (reverse causal order) for load balance.
#define PSTRIDE 68   // shorts; 136B row stride -> <=2-way bank aliasing on b128 reads
__global__ __launch_bounds__(256) void attn_fwd(const unsigned short* __restrict__ qb,
                                                const unsigned short* __restrict__ kbuf,
                                                const unsigned short* __restrict__ vt,
                                                unsigned short* __restrict__ y) {
    int bh = blockIdx.y;
    int b = bh >> 4, h = bh & 15, kvh = h >> 2;
    int wid = threadIdx.x >> 6, lane = threadIdx.x & 63;
    int qrow0 = (15 - (int)blockIdx.x) * 128 + wid * 32;
    const unsigned short* Q = qb + ((size_t)(b * 16 + h)) * 2048 * 64;
    const unsigned short* Kp = kbuf + ((size_t)(b * 4 + kvh)) * 2048 * 64;
    const unsigned short* Vp = vt + ((size_t)(b * 4 + kvh)) * 64 * 2048;
    const int fr = lane & 15, fk8 = (lane >> 4) * 8, rbase = (lane >> 4) * 4;

    bf16x8 qf[2][2];
#pragma unroll
    for (int m = 0; m < 2; ++m) {
        qf[m][0] = *(const bf16x8*)&Q[(qrow0 + m * 16 + fr) * 64 + fk8];
        qf[m][1] = *(const bf16x8*)&Q[(qrow0 + m * 16 + fr) * 64 + 32 + fk8];
    }

    f32x4 accO[2][4] = {};
    float mrun[2][4], lrun[2][4];
#pragma unroll
    for (int m = 0; m < 2; ++m)
#pragma unroll
        for (int r = 0; r < 4; ++r) { mrun[m][r] = -1e30f; lrun[m][r] = 0.0f; }

    __shared__ unsigned short sP[4][32 * PSTRIDE];
    unsigned short* myP = sP[wid];

    int nkt = (qrow0 + 95) >> 6;   // 64-key tiles covering keys 0..qrow0+31
    for (int kt = 0; kt < nkt; ++kt) {
        int kb0 = kt * 64;
        // prefetch V fragments early: latency hides under QK^T + softmax
        bf16x8 vf[4][2];
#pragma unroll
        for (int nd = 0; nd < 4; ++nd) {
            vf[nd][0] = *(const bf16x8*)&Vp[(nd * 16 + fr) * 2048 + kb0 + fk8];
            vf[nd][1] = *(const bf16x8*)&Vp[(nd * 16 + fr) * 2048 + kb0 + 32 + fk8];
        }
        // S = Q @ K^T  (4 key tiles x 2 k-halves, 16 MFMA)
        f32x4 s[2][4] = {};
#pragma unroll
        for (int j = 0; j < 4; ++j) {
            bf16x8 kf0 = *(const bf16x8*)&Kp[(kb0 + j * 16 + fr) * 64 + fk8];
            bf16x8 kf1 = *(const bf16x8*)&Kp[(kb0 + j * 16 + fr) * 64 + 32 + fk8];
#pragma unroll
            for (int m = 0; m < 2; ++m) {
                s[m][j] = MFMA16(qf[m][0], kf0, s[m][j]);
                s[m][j] = MFMA16(qf[m][1], kf1, s[m][j]);
            }
        }
        // causal mask only on diagonal tiles
        if (kb0 + 63 > qrow0) {
#pragma unroll
            for (int m = 0; m < 2; ++m)
#pragma unroll
                for (int j = 0; j < 4; ++j) {
                    int key = kb0 + j * 16 + fr;
#pragma unroll
                    for (int r = 0; r < 4; ++r)
                        if (key > qrow0 + m * 16 + rbase + r) s[m][j][r] = -1e30f;
                }
        }
        // online softmax: row-max over 16 lanes (4 shfl levels, 8 indep values each)
        float mt[2][4];
#pragma unroll
        for (int m = 0; m < 2; ++m)
#pragma unroll
            for (int r = 0; r < 4; ++r)
                mt[m][r] = fmaxf(fmaxf(s[m][0][r], s[m][1][r]), fmaxf(s[m][2][r], s[m][3][r]));
#pragma unroll
        for (int off = 1; off < 16; off <<= 1)
#pragma unroll
            for (int m = 0; m < 2; ++m)
#pragma unroll
                for (int r = 0; r < 4; ++r)
                    mt[m][r] = fmaxf(mt[m][r], __shfl_xor(mt[m][r], off));

        float sf[2][4], psum[2][4];
#pragma unroll
        for (int m = 0; m < 2; ++m)
#pragma unroll
            for (int r = 0; r < 4; ++r) {
                float mnew = fmaxf(mrun[m][r], mt[m][r]);
                sf[m][r] = __expf(mrun[m][r] - mnew);
                mrun[m][r] = mnew;
                psum[m][r] = 0.0f;
            }
#pragma unroll
        for (int m = 0; m < 2; ++m)
#pragma unroll
            for (int j = 0; j < 4; ++j)
#pragma unroll
                for (int r = 0; r < 4; ++r) {
                    float p = __expf(s[m][j][r] - mrun[m][r]);
                    psum[m][r] += p;
                    myP[(m * 16 + rbase + r) * PSTRIDE + j * 16 + fr] = f2bf(p);
                }
#pragma unroll
        for (int off = 1; off < 16; off <<= 1)
#pragma unroll
            for (int m = 0; m < 2; ++m)
#pragma unroll
                for (int r = 0; r < 4; ++r)
                    psum[m][r] += __shfl_xor(psum[m][r], off);
#pragma unroll
        for (int m = 0; m < 2; ++m)
#pragma unroll
            for (int r = 0; r < 4; ++r)
                lrun[m][r] = lrun[m][r] * sf[m][r] + psum[m][r];
#pragma unroll
        for (int m = 0; m < 2; ++m)
#pragma unroll
            for (int nd = 0; nd < 4; ++nd)
#pragma unroll
                for (int r = 0; r < 4; ++r) accO[m][nd][r] *= sf[m][r];

        // P relayout via per-wave LDS round trip -> A fragments
        asm volatile("s_waitcnt lgkmcnt(0)" ::: "memory");
        __builtin_amdgcn_sched_barrier(0);
#pragma unroll
        for (int m = 0; m < 2; ++m) {
            bf16x8 pf0 = *(const bf16x8*)&myP[(m * 16 + fr) * PSTRIDE + fk8];
            bf16x8 pf1 = *(const bf16x8*)&myP[(m * 16 + fr) * PSTRIDE + 32 + fk8];
#pragma unroll
            for (int nd = 0; nd < 4; ++nd) {
                accO[m][nd] = MFMA16(pf0, vf[nd][0], accO[m][nd]);
                accO[m][nd] = MFMA16(pf1, vf[nd][1], accO[m][nd]);
            }
        }
        asm volatile("" ::: "memory");   // keep next tile's sP writes after these reads
    }

    // finalize: y[b][t][h*64+d] bf16
#pragma unroll
    for (int m = 0; m < 2; ++m)
#pragma unroll
        for (int r = 0; r < 4; ++r) {
            float inv = 1.0f / lrun[m][r];
            size_t rowoff = ((size_t)b * 2048 + (qrow0 + m * 16 + rbase + r)) * 1024 + h * 64;
#pragma unroll
            for (int nd = 0; nd < 4; ++nd)
                y[rowoff + nd * 16 + fr] = f2bf(accO[m][nd][r] * inv);
        }
}

extern "C" void kernel_launch(void* const* d_in, const int* in_sizes, int n_in,
                              void* d_out, int out_size, void* d_ws, size_t ws_size,
                              hipStream_t stream) {
    const float* x = (const float*)d_in[0];
    const float* wq = (const float*)d_in[1];
    const float* wk = (const float*)d_in[2];
    const float* wv = (const float*)d_in[3];
    const float* wo = (const float*)d_in[4];
    float* out = (float*)d_out;

    char* ws = (char*)d_ws;
    size_t off = 0;
    auto alloc = [&](size_t bytes) {
        void* p = ws + off;
        off += (bytes + 255) & ~(size_t)255;
        return p;
    };
    unsigned short* xb    = (unsigned short*)alloc(8192ull * 1024 * 2);
    unsigned short* wqkvb = (unsigned short*)alloc(1536ull * 1024 * 2);
    unsigned short* wob   = (unsigned short*)alloc(1024ull * 1024 * 2);
    float*          qkv   = (float*)alloc(8192ull * 1536 * 4);
    float2*         tbl   = (float2*)alloc(2048ull * 32 * 8);
    unsigned short* qb    = (unsigned short*)alloc(8192ull * 1024 * 2);
    unsigned short* kb    = (unsigned short*)alloc(4ull * 4 * 2048 * 64 * 2);
    unsigned short* vb    = (unsigned short*)alloc(4ull * 4 * 2048 * 64 * 2);
    unsigned short* vt    = (unsigned short*)alloc(4ull * 4 * 64 * 2048 * 2);
    unsigned short* ybf   = (unsigned short*)qkv;  // alias: qkv dead after rope_norm

    cvt_f32_bf16<<<(2097152 + 255) / 256, 256, 0, stream>>>((const float4*)x, (ushort4*)xb, 2097152);
    cvt_f32_bf16<<<(262144 + 255) / 256, 256, 0, stream>>>((const float4*)wq, (ushort4*)wqkvb, 262144);
    cvt_f32_bf16<<<(65536 + 255) / 256, 256, 0, stream>>>((const float4*)wk, (ushort4*)(wqkvb + 1048576), 65536);
    cvt_f32_bf16<<<(65536 + 255) / 256, 256, 0, stream>>>((const float4*)wv, (ushort4*)(wqkvb + 1310720), 65536);
    cvt_f32_bf16<<<(262144 + 255) / 256, 256, 0, stream>>>((const float4*)wo, (ushort4*)wob, 262144);

    trig_table<<<256, 256, 0, stream>>>(tbl);

    gemm_bt<<<dim3(64, 12), 256, 0, stream>>>(xb, wqkvb, qkv, 8192, 1536, 1024);

    rope_norm<<<(8192 * 24) / 4, 256, 0, stream>>>(qkv, tbl, qb, kb, vb);

    vtrans<<<dim3(32, 16), 256, 0, stream>>>(vb, vt);

    attn_fwd<<<dim3(16, 64), 256, 0, stream>>>(qb, kb, vt, ybf);

    gemm_bt<<<dim3(64, 8), 256, 0, stream>>>(ybf, wob, out, 8192, 1024, 1024);
}

// Round 3
// 338.095 us; speedup vs baseline: 1.6485x; 1.0111x over previous
//
#include <hip/hip_runtime.h>
#include <hip/hip_bf16.h>

typedef __attribute__((ext_vector_type(8))) __bf16 bf16x8;
typedef __attribute__((ext_vector_type(4))) float f32x4;

#define MFMA16(a, b, c) __builtin_amdgcn_mfma_f32_16x16x32_bf16((a), (b), (c), 0, 0, 0)

__device__ __forceinline__ unsigned short f2bf(float f) {
    unsigned u = __builtin_bit_cast(unsigned, f);
    u = (u + 0x7fffu + ((u >> 16) & 1u)) >> 16;
    return (unsigned short)u;
}

__device__ __forceinline__ void gll16(const void* g, void* l) {
    __builtin_amdgcn_global_load_lds((const __attribute__((address_space(1))) void*)g,
                                     (__attribute__((address_space(3))) void*)l, 16, 0, 0);
}

// ---------------- fp32 -> bf16 convert (vectorized, G13) ----------------
__global__ __launch_bounds__(256) void cvt_f32_bf16(const float4* __restrict__ in,
                                                    ushort4* __restrict__ out, int n4) {
    int i = blockIdx.x * 256 + threadIdx.x;
    if (i >= n4) return;
    float4 v = in[i];
    ushort4 o;
    o.x = f2bf(v.x); o.y = f2bf(v.y); o.z = f2bf(v.z); o.w = f2bf(v.w);
    out[i] = o;
}

// ---------------- RoPE cos/sin table: tbl[t*32+j] = (cos, sin) ----------------
__global__ __launch_bounds__(256) void trig_table(float2* __restrict__ tbl) {
    int i = blockIdx.x * 256 + threadIdx.x;   // 65536 = 2048*32
    int t = i >> 5, j = i & 31;
    float inv = powf(10000.0f, -(float)(2 * j) * (1.0f / 64.0f));
    float a = (float)t * inv;
    tbl[i] = make_float2(cosf(a), sinf(a));
}

// ---------------- GEMM: C(MxN) = A(MxK) @ Bt(NxK)^T, bf16 in, fp32 out ----------------
__global__ __launch_bounds__(256) void gemm_bt(const unsigned short* __restrict__ A,
                                               const unsigned short* __restrict__ Bt,
                                               float* __restrict__ C, int M, int N, int K) {
    __shared__ unsigned short As[2][128 * 32];
    __shared__ unsigned short Bs[2][128 * 32];
    const int tid = threadIdx.x;
    const int wid = tid >> 6, lane = tid & 63;
    const size_t brow = (size_t)blockIdx.x * 128, bcol = (size_t)blockIdx.y * 128;
    const int nkt = K >> 5;

    auto stage = [&](int buf, int kt) {
#pragma unroll
        for (int j = 0; j < 2; ++j) {
            int e = (j * 256 + tid) * 8;
            int r = e >> 5, c = e & 31;
            gll16(A + (brow + r) * K + kt * 32 + c, &As[buf][e]);
        }
#pragma unroll
        for (int j = 0; j < 2; ++j) {
            int e = (j * 256 + tid) * 8;
            int r = e >> 5, c = e & 31;
            gll16(Bt + (bcol + r) * K + kt * 32 + c, &Bs[buf][e]);
        }
    };

    f32x4 acc[4][4] = {};
    const int wm = (wid >> 1) * 64, wn = (wid & 1) * 64;
    const int fr = lane & 15, fk = (lane >> 4) * 8;

    stage(0, 0);
    for (int kt = 0; kt < nkt; ++kt) {
        __syncthreads();
        if (kt + 1 < nkt) stage((kt + 1) & 1, kt + 1);
        const int buf = kt & 1;
        bf16x8 af[4], bfr[4];
#pragma unroll
        for (int i = 0; i < 4; ++i)
            af[i] = *(const bf16x8*)&As[buf][(wm + i * 16 + fr) * 32 + fk];
#pragma unroll
        for (int i = 0; i < 4; ++i)
            bfr[i] = *(const bf16x8*)&Bs[buf][(wn + i * 16 + fr) * 32 + fk];
#pragma unroll
        for (int i = 0; i < 4; ++i)
#pragma unroll
            for (int j = 0; j < 4; ++j)
                acc[i][j] = MFMA16(af[i], bfr[j], acc[i][j]);
    }

    const int orow = (lane >> 4) * 4, ocol = lane & 15;
#pragma unroll
    for (int i = 0; i < 4; ++i)
#pragma unroll
        for (int j = 0; j < 4; ++j)
#pragma unroll
            for (int r = 0; r < 4; ++r)
                C[(brow + wm + i * 16 + orow + r) * N + (bcol + wn + j * 16 + ocol)] =
                    acc[i][j][r];
}

// ---------------- RoPE + QK-RMSNorm + layout split (q pre-scaled by 1/sqrt(D)) ----------------
__global__ __launch_bounds__(256) void rope_norm(const float* __restrict__ qkv,
                                                 const float2* __restrict__ tbl,
                                                 unsigned short* __restrict__ qb,
                                                 unsigned short* __restrict__ kb,
                                                 unsigned short* __restrict__ vb) {
    int unit = blockIdx.x * 4 + (threadIdx.x >> 6);
    int lane = threadIdx.x & 63;
    int row = unit / 24;
    int hh = unit - row * 24;
    int b = row >> 11, t = row & 2047;
    int col = (hh < 16) ? hh * 64 : (hh < 20 ? 1024 + (hh - 16) * 64 : 1280 + (hh - 20) * 64);
    float x = qkv[(size_t)row * 1536 + col + lane];
    float o = x;
    if (hh < 20) {
        float partner = __shfl_xor(x, 1);
        float2 cs = tbl[t * 32 + (lane >> 1)];
        float sgn = (lane & 1) ? cs.y : -cs.y;
        o = x * cs.x + partner * sgn;
        float ss = o * o;
#pragma unroll
        for (int off = 1; off < 64; off <<= 1) ss += __shfl_xor(ss, off);
        o = o * rsqrtf(ss * (1.0f / 64.0f) + 1e-6f);
        if (hh < 16) o *= 0.125f;   // fold attention scale 1/sqrt(64) into q
    }
    unsigned short ob = f2bf(o);
    if (hh < 16)
        qb[(((size_t)(b * 16 + hh)) * 2048 + t) * 64 + lane] = ob;
    else if (hh < 20)
        kb[(((size_t)(b * 4 + (hh - 16))) * 2048 + t) * 64 + lane] = ob;
    else
        vb[(((size_t)(b * 4 + (hh - 20))) * 2048 + t) * 64 + lane] = ob;
}

// ---------------- V transpose: [B*KVH][T][D] -> [B*KVH][D][T] ----------------
__global__ __launch_bounds__(256) void vtrans(const unsigned short* __restrict__ vb,
                                              unsigned short* __restrict__ vt) {
    __shared__ unsigned short tile[64][72];
    int bk = blockIdx.y, t0 = blockIdx.x * 64;
    int i = threadIdx.x >> 2, c0 = (threadIdx.x & 3) * 16;
    const unsigned short* src = vb + ((size_t)bk * 2048 + t0) * 64;
#pragma unroll
    for (int j = 0; j < 16; ++j) tile[i][c0 + j] = src[i * 64 + c0 + j];
    __syncthreads();
    unsigned short* dst = vt + (size_t)bk * 64 * 2048 + (size_t)i * 2048 + t0 + c0;
#pragma unroll
    for (int j = 0; j < 16; ++j) dst[j] = tile[c0 + j][i];
}

// ---------------- causal flash attention, static-max softmax ----------------
// Scores bounded: |q_hat|=1 (rms-normed, pre-scaled 1/sqrt(D)), |k|=8 -> s <= 8.
// p = exp(s-8); denominator via MFMA against all-ones fragment. No cross-lane ops.
// Swapped QK^T (mfma(K,Q)): lane holds 4 consecutive keys -> packed b64 P-writes.
// grid: (16, B*H), 4 waves/block, each wave owns 32 q rows; KVBLK=64, heavy-first.
#define PSTRIDE 76   // shorts; 152B rows: b128 reads conflict-free per quarter-wave
__global__ __launch_bounds__(256) void attn_fwd(const unsigned short* __restrict__ qb,
                                                const unsigned short* __restrict__ kbuf,
                                                const unsigned short* __restrict__ vt,
                                                unsigned short* __restrict__ y) {
    int bh = blockIdx.y;
    int b = bh >> 4, h = bh & 15, kvh = h >> 2;
    int wid = threadIdx.x >> 6, lane = threadIdx.x & 63;
    int qrow0 = (15 - (int)blockIdx.x) * 128 + wid * 32;
    const unsigned short* Q = qb + ((size_t)(b * 16 + h)) * 2048 * 64;
    const unsigned short* Kp = kbuf + ((size_t)(b * 4 + kvh)) * 2048 * 64;
    const unsigned short* Vp = vt + ((size_t)(b * 4 + kvh)) * 64 * 2048;
    const int fr = lane & 15, fk8 = (lane >> 4) * 8, rbase = (lane >> 4) * 4;

    bf16x8 qf[2][2];
#pragma unroll
    for (int m = 0; m < 2; ++m) {
        qf[m][0] = *(const bf16x8*)&Q[(qrow0 + m * 16 + fr) * 64 + fk8];
        qf[m][1] = *(const bf16x8*)&Q[(qrow0 + m * 16 + fr) * 64 + 32 + fk8];
    }

    bf16x8 onesf;
#pragma unroll
    for (int i = 0; i < 8; ++i) onesf[i] = (__bf16)1.0f;

    f32x4 accO[2][4] = {};
    f32x4 accL[2] = {};

    __shared__ unsigned short sP[4][32 * PSTRIDE];
    unsigned short* myP = sP[wid];

    int nkt = (qrow0 + 95) >> 6;   // 64-key tiles covering keys 0..qrow0+31
    for (int kt = 0; kt < nkt; ++kt) {
        int kb0 = kt * 64;
        // prefetch V fragments early: latency hides under QK^T + exp
        bf16x8 vf[4][2];
#pragma unroll
        for (int nd = 0; nd < 4; ++nd) {
            vf[nd][0] = *(const bf16x8*)&Vp[(nd * 16 + fr) * 2048 + kb0 + fk8];
            vf[nd][1] = *(const bf16x8*)&Vp[(nd * 16 + fr) * 2048 + kb0 + 32 + fk8];
        }
        // swapped S^T = K @ Q^T: out col = q (fr), row = key (rbase+r)
        f32x4 s[2][4] = {};
#pragma unroll
        for (int j = 0; j < 4; ++j) {
            bf16x8 kf0 = *(const bf16x8*)&Kp[(kb0 + j * 16 + fr) * 64 + fk8];
            bf16x8 kf1 = *(const bf16x8*)&Kp[(kb0 + j * 16 + fr) * 64 + 32 + fk8];
#pragma unroll
            for (int m = 0; m < 2; ++m) {
                s[m][j] = MFMA16(kf0, qf[m][0], s[m][j]);
                s[m][j] = MFMA16(kf1, qf[m][1], s[m][j]);
            }
        }
        // p = exp(s - 8) = exp2(s*log2e - 8*log2e); mask only on diagonal tiles
        const bool diag = (kb0 + 63 > qrow0);
#pragma unroll
        for (int m = 0; m < 2; ++m) {
            int q = qrow0 + m * 16 + fr;
#pragma unroll
            for (int j = 0; j < 4; ++j) {
                ushort4 w;
#pragma unroll
                for (int r = 0; r < 4; ++r) {
                    float p = __builtin_exp2f(fmaf(s[m][j][r], 1.44269504f, -11.54156036f));
                    if (diag && (kb0 + j * 16 + rbase + r > q)) p = 0.0f;
                    ((unsigned short*)&w)[r] = f2bf(p);
                }
                *(ushort4*)&myP[(m * 16 + fr) * PSTRIDE + j * 16 + rbase] = w;
            }
        }
        // P relayout via per-wave LDS round trip -> A fragments
        asm volatile("s_waitcnt lgkmcnt(0)" ::: "memory");
        __builtin_amdgcn_sched_barrier(0);
#pragma unroll
        for (int m = 0; m < 2; ++m) {
            bf16x8 pf0 = *(const bf16x8*)&myP[(m * 16 + fr) * PSTRIDE + fk8];
            bf16x8 pf1 = *(const bf16x8*)&myP[(m * 16 + fr) * PSTRIDE + 32 + fk8];
#pragma unroll
            for (int nd = 0; nd < 4; ++nd) {
                accO[m][nd] = MFMA16(pf0, vf[nd][0], accO[m][nd]);
                accO[m][nd] = MFMA16(pf1, vf[nd][1], accO[m][nd]);
            }
            accL[m] = MFMA16(pf0, onesf, accL[m]);
            accL[m] = MFMA16(pf1, onesf, accL[m]);
        }
        asm volatile("" ::: "memory");   // keep next tile's sP writes after these reads
    }

    // finalize: y[b][t][h*64+d] bf16
#pragma unroll
    for (int m = 0; m < 2; ++m)
#pragma unroll
        for (int r = 0; r < 4; ++r) {
            float inv = 1.0f / accL[m][r];
            size_t rowoff = ((size_t)b * 2048 + (qrow0 + m * 16 + rbase + r)) * 1024 + h * 64;
#pragma unroll
            for (int nd = 0; nd < 4; ++nd)
                y[rowoff + nd * 16 + fr] = f2bf(accO[m][nd][r] * inv);
        }
}

extern "C" void kernel_launch(void* const* d_in, const int* in_sizes, int n_in,
                              void* d_out, int out_size, void* d_ws, size_t ws_size,
                              hipStream_t stream) {
    const float* x = (const float*)d_in[0];
    const float* wq = (const float*)d_in[1];
    const float* wk = (const float*)d_in[2];
    const float* wv = (const float*)d_in[3];
    const float* wo = (const float*)d_in[4];
    float* out = (float*)d_out;

    char* ws = (char*)d_ws;
    size_t off = 0;
    auto alloc = [&](size_t bytes) {
        void* p = ws + off;
        off += (bytes + 255) & ~(size_t)255;
        return p;
    };
    unsigned short* xb    = (unsigned short*)alloc(8192ull * 1024 * 2);
    unsigned short* wqkvb = (unsigned short*)alloc(1536ull * 1024 * 2);
    unsigned short* wob   = (unsigned short*)alloc(1024ull * 1024 * 2);
    float*          qkv   = (float*)alloc(8192ull * 1536 * 4);
    float2*         tbl   = (float2*)alloc(2048ull * 32 * 8);
    unsigned short* qb    = (unsigned short*)alloc(8192ull * 1024 * 2);
    unsigned short* kb    = (unsigned short*)alloc(4ull * 4 * 2048 * 64 * 2);
    unsigned short* vb    = (unsigned short*)alloc(4ull * 4 * 2048 * 64 * 2);
    unsigned short* vt    = (unsigned short*)alloc(4ull * 4 * 64 * 2048 * 2);
    unsigned short* ybf   = (unsigned short*)qkv;  // alias: qkv dead after rope_norm

    cvt_f32_bf16<<<(2097152 + 255) / 256, 256, 0, stream>>>((const float4*)x, (ushort4*)xb, 2097152);
    cvt_f32_bf16<<<(262144 + 255) / 256, 256, 0, stream>>>((const float4*)wq, (ushort4*)wqkvb, 262144);
    cvt_f32_bf16<<<(65536 + 255) / 256, 256, 0, stream>>>((const float4*)wk, (ushort4*)(wqkvb + 1048576), 65536);
    cvt_f32_bf16<<<(65536 + 255) / 256, 256, 0, stream>>>((const float4*)wv, (ushort4*)(wqkvb + 1310720), 65536);
    cvt_f32_bf16<<<(262144 + 255) / 256, 256, 0, stream>>>((const float4*)wo, (ushort4*)wob, 262144);

    trig_table<<<256, 256, 0, stream>>>(tbl);

    gemm_bt<<<dim3(64, 12), 256, 0, stream>>>(xb, wqkvb, qkv, 8192, 1536, 1024);

    rope_norm<<<(8192 * 24) / 4, 256, 0, stream>>>(qkv, tbl, qb, kb, vb);

    vtrans<<<dim3(32, 16), 256, 0, stream>>>(vb, vt);

    attn_fwd<<<dim3(16, 64), 256, 0, stream>>>(qb, kb, vt, ybf);

    gemm_bt<<<dim3(64, 8), 256, 0, stream>>>(ybf, wob, out, 8192, 1024, 1024);
}

// Round 4
// 242.179 us; speedup vs baseline: 2.3014x; 1.3961x over previous
//
#include <hip/hip_runtime.h>
#include <hip/hip_bf16.h>

typedef __attribute__((ext_vector_type(8))) __bf16 bf16x8;
typedef __attribute__((ext_vector_type(4))) float f32x4;

#define MFMA16(a, b, c) __builtin_amdgcn_mfma_f32_16x16x32_bf16((a), (b), (c), 0, 0, 0)

__device__ __forceinline__ unsigned short f2bf(float f) {
    unsigned u = __builtin_bit_cast(unsigned, f);
    u = (u + 0x7fffu + ((u >> 16) & 1u)) >> 16;
    return (unsigned short)u;
}

__device__ __forceinline__ void gll16(const void* g, void* l) {
    __builtin_amdgcn_global_load_lds((const __attribute__((address_space(1))) void*)g,
                                     (__attribute__((address_space(3))) void*)l, 16, 0, 0);
}

// ---------------- fp32 -> bf16 convert (vectorized, G13) ----------------
__global__ __launch_bounds__(256) void cvt_f32_bf16(const float4* __restrict__ in,
                                                    ushort4* __restrict__ out, int n4) {
    int i = blockIdx.x * 256 + threadIdx.x;
    if (i >= n4) return;
    float4 v = in[i];
    ushort4 o;
    o.x = f2bf(v.x); o.y = f2bf(v.y); o.z = f2bf(v.z); o.w = f2bf(v.w);
    out[i] = o;
}

// ---------------- RoPE cos/sin table: tbl[t*32+j] = (cos, sin) ----------------
__global__ __launch_bounds__(256) void trig_table(float2* __restrict__ tbl) {
    int i = blockIdx.x * 256 + threadIdx.x;   // 65536 = 2048*32
    int t = i >> 5, j = i & 31;
    float inv = powf(10000.0f, -(float)(2 * j) * (1.0f / 64.0f));
    float a = (float)t * inv;
    tbl[i] = make_float2(cosf(a), sinf(a));
}

// ---------------- GEMM: C(MxN) = A(MxK) @ Bt(NxK)^T, bf16 in, fp32 out ----------------
__global__ __launch_bounds__(256) void gemm_bt(const unsigned short* __restrict__ A,
                                               const unsigned short* __restrict__ Bt,
                                               float* __restrict__ C, int M, int N, int K) {
    __shared__ unsigned short As[2][128 * 32];
    __shared__ unsigned short Bs[2][128 * 32];
    const int tid = threadIdx.x;
    const int wid = tid >> 6, lane = tid & 63;
    const size_t brow = (size_t)blockIdx.x * 128, bcol = (size_t)blockIdx.y * 128;
    const int nkt = K >> 5;

    auto stage = [&](int buf, int kt) {
#pragma unroll
        for (int j = 0; j < 2; ++j) {
            int e = (j * 256 + tid) * 8;
            int r = e >> 5, c = e & 31;
            gll16(A + (brow + r) * K + kt * 32 + c, &As[buf][e]);
        }
#pragma unroll
        for (int j = 0; j < 2; ++j) {
            int e = (j * 256 + tid) * 8;
            int r = e >> 5, c = e & 31;
            gll16(Bt + (bcol + r) * K + kt * 32 + c, &Bs[buf][e]);
        }
    };

    f32x4 acc[4][4] = {};
    const int wm = (wid >> 1) * 64, wn = (wid & 1) * 64;
    const int fr = lane & 15, fk = (lane >> 4) * 8;

    stage(0, 0);
    for (int kt = 0; kt < nkt; ++kt) {
        __syncthreads();
        if (kt + 1 < nkt) stage((kt + 1) & 1, kt + 1);
        const int buf = kt & 1;
        bf16x8 af[4], bfr[4];
#pragma unroll
        for (int i = 0; i < 4; ++i)
            af[i] = *(const bf16x8*)&As[buf][(wm + i * 16 + fr) * 32 + fk];
#pragma unroll
        for (int i = 0; i < 4; ++i)
            bfr[i] = *(const bf16x8*)&Bs[buf][(wn + i * 16 + fr) * 32 + fk];
#pragma unroll
        for (int i = 0; i < 4; ++i)
#pragma unroll
            for (int j = 0; j < 4; ++j)
                acc[i][j] = MFMA16(af[i], bfr[j], acc[i][j]);
    }

    const int orow = (lane >> 4) * 4, ocol = lane & 15;
#pragma unroll
    for (int i = 0; i < 4; ++i)
#pragma unroll
        for (int j = 0; j < 4; ++j)
#pragma unroll
            for (int r = 0; r < 4; ++r)
                C[(brow + wm + i * 16 + orow + r) * N + (bcol + wn + j * 16 + ocol)] =
                    acc[i][j][r];
}

// ---------------- RoPE + QK-RMSNorm + layout split (q pre-scaled by 1/sqrt(D)) ----------------
__global__ __launch_bounds__(256) void rope_norm(const float* __restrict__ qkv,
                                                 const float2* __restrict__ tbl,
                                                 unsigned short* __restrict__ qb,
                                                 unsigned short* __restrict__ kb,
                                                 unsigned short* __restrict__ vb) {
    int unit = blockIdx.x * 4 + (threadIdx.x >> 6);
    int lane = threadIdx.x & 63;
    int row = unit / 24;
    int hh = unit - row * 24;
    int b = row >> 11, t = row & 2047;
    int col = (hh < 16) ? hh * 64 : (hh < 20 ? 1024 + (hh - 16) * 64 : 1280 + (hh - 20) * 64);
    float x = qkv[(size_t)row * 1536 + col + lane];
    float o = x;
    if (hh < 20) {
        float partner = __shfl_xor(x, 1);
        float2 cs = tbl[t * 32 + (lane >> 1)];
        float sgn = (lane & 1) ? cs.y : -cs.y;
        o = x * cs.x + partner * sgn;
        float ss = o * o;
#pragma unroll
        for (int off = 1; off < 64; off <<= 1) ss += __shfl_xor(ss, off);
        o = o * rsqrtf(ss * (1.0f / 64.0f) + 1e-6f);
        if (hh < 16) o *= 0.125f;   // fold attention scale 1/sqrt(64) into q
    }
    unsigned short ob = f2bf(o);
    if (hh < 16)
        qb[(((size_t)(b * 16 + hh)) * 2048 + t) * 64 + lane] = ob;
    else if (hh < 20)
        kb[(((size_t)(b * 4 + (hh - 16))) * 2048 + t) * 64 + lane] = ob;
    else
        vb[(((size_t)(b * 4 + (hh - 20))) * 2048 + t) * 64 + lane] = ob;
}

// ---------------- V transpose: [B*KVH][T][D] -> [B*KVH][D][T] ----------------
__global__ __launch_bounds__(256) void vtrans(const unsigned short* __restrict__ vb,
                                              unsigned short* __restrict__ vt) {
    __shared__ unsigned short tile[64][72];
    int bk = blockIdx.y, t0 = blockIdx.x * 64;
    int i = threadIdx.x >> 2, c0 = (threadIdx.x & 3) * 16;
    const unsigned short* src = vb + ((size_t)bk * 2048 + t0) * 64;
#pragma unroll
    for (int j = 0; j < 16; ++j) tile[i][c0 + j] = src[i * 64 + c0 + j];
    __syncthreads();
    unsigned short* dst = vt + (size_t)bk * 64 * 2048 + (size_t)i * 2048 + t0 + c0;
#pragma unroll
    for (int j = 0; j < 16; ++j) dst[j] = tile[c0 + j][i];
}

// ---------------- causal flash attention, static-max softmax, LDS-staged K/V ----------------
// K/V tiles (64 keys) staged once per block via global_load_lds, shared by 4 waves
// (4x global-traffic cut vs per-wave reads). XOR chunk swizzle: LDS dest linear,
// global src pre-swizzled (rule #21); ds_read side applies same XOR -> 2-way max
// per quarter-wave. Bijective XCD-chunk swizzle: 8 bh / XCD = 2 KV groups = 1MB L2.
#define PSTRIDE 76
__global__ __launch_bounds__(256) void attn_fwd(const unsigned short* __restrict__ qb,
                                                const unsigned short* __restrict__ kbuf,
                                                const unsigned short* __restrict__ vt,
                                                unsigned short* __restrict__ y) {
    // XCD-chunked bijective swizzle (nwg=1024, 8 XCDs)
    int orig = blockIdx.x;
    int wg = (orig & 7) * 128 + (orig >> 3);
    int bh = wg >> 4, qt = wg & 15;
    int qbase = (15 - qt) * 128;          // heavy-first within each bh
    int b = bh >> 4, h = bh & 15, kvh = h >> 2;
    int tid = threadIdx.x, wid = tid >> 6, lane = tid & 63;
    int qrow0 = qbase + wid * 32;
    const unsigned short* Q = qb + ((size_t)(b * 16 + h)) * 2048 * 64;
    const unsigned short* Kp = kbuf + ((size_t)(b * 4 + kvh)) * 2048 * 64;
    const unsigned short* Vp = vt + ((size_t)(b * 4 + kvh)) * 64 * 2048;
    const int fr = lane & 15, fk8 = (lane >> 4) * 8, rbase = (lane >> 4) * 4;

    __shared__ unsigned short Klds[2][4096];   // [64 keys][64 d], chunk-swizzled
    __shared__ unsigned short Vlds[2][4096];   // [64 d][64 keys], chunk-swizzled
    __shared__ unsigned short sP[4][32 * PSTRIDE];
    unsigned short* myP = sP[wid];

    // stage one 64-key K tile + V^T tile into LDS (16KB), src pre-swizzled
    auto stage = [&](int buf, int kt) {
#pragma unroll
        for (int j = 0; j < 2; ++j) {
            int t = j * 256 + tid;
            int k = t >> 3, c = (t & 7) ^ (k & 7);
            gll16(Kp + ((size_t)(kt * 64 + k)) * 64 + c * 8, &Klds[buf][t * 8]);
        }
#pragma unroll
        for (int j = 0; j < 2; ++j) {
            int t = j * 256 + tid;
            int d = t >> 3, c = (t & 7) ^ (d & 7);
            gll16(Vp + (size_t)d * 2048 + kt * 64 + c * 8, &Vlds[buf][t * 8]);
        }
    };

    bf16x8 qf[2][2];
#pragma unroll
    for (int m = 0; m < 2; ++m) {
        qf[m][0] = *(const bf16x8*)&Q[(qrow0 + m * 16 + fr) * 64 + fk8];
        qf[m][1] = *(const bf16x8*)&Q[(qrow0 + m * 16 + fr) * 64 + 32 + fk8];
    }

    bf16x8 onesf;
#pragma unroll
    for (int i = 0; i < 8; ++i) onesf[i] = (__bf16)1.0f;

    f32x4 accO[2][4] = {};
    f32x4 accL[2] = {};

    const int nkt = (qbase + 191) >> 6;    // kv tiles covering keys 0..qbase+127
    stage(0, 0);
    for (int kt = 0; kt < nkt; ++kt) {
        __syncthreads();                   // drains stage(kt) vmcnt; guards buf reuse
        if (kt + 1 < nkt) stage((kt + 1) & 1, kt + 1);
        const int cur = kt & 1;
        const int kb0 = kt * 64;
        if (kb0 <= qrow0 + 31) {           // wave-uniform causal skip (barriers stay outside)
            // swapped S^T = K @ Q^T from LDS (swizzled reads)
            f32x4 s[2][4] = {};
#pragma unroll
            for (int j = 0; j < 4; ++j) {
                int row = j * 16 + fr, sw = (row & 7) << 3;
                bf16x8 kf0 = *(const bf16x8*)&Klds[cur][row * 64 + (fk8 ^ sw)];
                bf16x8 kf1 = *(const bf16x8*)&Klds[cur][row * 64 + ((32 + fk8) ^ sw)];
#pragma unroll
                for (int m = 0; m < 2; ++m) {
                    s[m][j] = MFMA16(kf0, qf[m][0], s[m][j]);
                    s[m][j] = MFMA16(kf1, qf[m][1], s[m][j]);
                }
            }
            // p = exp(s-8): static max (|q_hat.k| <= 8 after rms-norm + 1/sqrt(D))
            const bool diag = (kb0 + 63 > qrow0);
#pragma unroll
            for (int m = 0; m < 2; ++m) {
                int q = qrow0 + m * 16 + fr;
#pragma unroll
                for (int j = 0; j < 4; ++j) {
                    ushort4 w;
#pragma unroll
                    for (int r = 0; r < 4; ++r) {
                        float p = __builtin_exp2f(fmaf(s[m][j][r], 1.44269504f, -11.54156036f));
                        if (diag && (kb0 + j * 16 + rbase + r > q)) p = 0.0f;
                        ((unsigned short*)&w)[r] = f2bf(p);
                    }
                    *(ushort4*)&myP[(m * 16 + fr) * PSTRIDE + j * 16 + rbase] = w;
                }
            }
            // V fragments from LDS (swizzled)
            bf16x8 vf[4][2];
#pragma unroll
            for (int nd = 0; nd < 4; ++nd) {
                int row = nd * 16 + fr, sw = (row & 7) << 3;
                vf[nd][0] = *(const bf16x8*)&Vlds[cur][row * 64 + (fk8 ^ sw)];
                vf[nd][1] = *(const bf16x8*)&Vlds[cur][row * 64 + ((32 + fk8) ^ sw)];
            }
            // P relayout via per-wave LDS round trip -> A fragments
            asm volatile("s_waitcnt lgkmcnt(0)" ::: "memory");
            __builtin_amdgcn_sched_barrier(0);
#pragma unroll
            for (int m = 0; m < 2; ++m) {
                bf16x8 pf0 = *(const bf16x8*)&myP[(m * 16 + fr) * PSTRIDE + fk8];
                bf16x8 pf1 = *(const bf16x8*)&myP[(m * 16 + fr) * PSTRIDE + 32 + fk8];
#pragma unroll
                for (int nd = 0; nd < 4; ++nd) {
                    accO[m][nd] = MFMA16(pf0, vf[nd][0], accO[m][nd]);
                    accO[m][nd] = MFMA16(pf1, vf[nd][1], accO[m][nd]);
                }
                accL[m] = MFMA16(pf0, onesf, accL[m]);
                accL[m] = MFMA16(pf1, onesf, accL[m]);
            }
            asm volatile("" ::: "memory");
        }
    }

    // finalize: y[b][t][h*64+d] bf16
#pragma unroll
    for (int m = 0; m < 2; ++m)
#pragma unroll
        for (int r = 0; r < 4; ++r) {
            float inv = 1.0f / accL[m][r];
            size_t rowoff = ((size_t)b * 2048 + (qrow0 + m * 16 + rbase + r)) * 1024 + h * 64;
#pragma unroll
            for (int nd = 0; nd < 4; ++nd)
                y[rowoff + nd * 16 + fr] = f2bf(accO[m][nd][r] * inv);
        }
}

extern "C" void kernel_launch(void* const* d_in, const int* in_sizes, int n_in,
                              void* d_out, int out_size, void* d_ws, size_t ws_size,
                              hipStream_t stream) {
    const float* x = (const float*)d_in[0];
    const float* wq = (const float*)d_in[1];
    const float* wk = (const float*)d_in[2];
    const float* wv = (const float*)d_in[3];
    const float* wo = (const float*)d_in[4];
    float* out = (float*)d_out;

    char* ws = (char*)d_ws;
    size_t off = 0;
    auto alloc = [&](size_t bytes) {
        void* p = ws + off;
        off += (bytes + 255) & ~(size_t)255;
        return p;
    };
    unsigned short* xb    = (unsigned short*)alloc(8192ull * 1024 * 2);
    unsigned short* wqkvb = (unsigned short*)alloc(1536ull * 1024 * 2);
    unsigned short* wob   = (unsigned short*)alloc(1024ull * 1024 * 2);
    float*          qkv   = (float*)alloc(8192ull * 1536 * 4);
    float2*         tbl   = (float2*)alloc(2048ull * 32 * 8);
    unsigned short* qb    = (unsigned short*)alloc(8192ull * 1024 * 2);
    unsigned short* kb    = (unsigned short*)alloc(4ull * 4 * 2048 * 64 * 2);
    unsigned short* vb    = (unsigned short*)alloc(4ull * 4 * 2048 * 64 * 2);
    unsigned short* vt    = (unsigned short*)alloc(4ull * 4 * 64 * 2048 * 2);
    unsigned short* ybf   = (unsigned short*)qkv;  // alias: qkv dead after rope_norm

    cvt_f32_bf16<<<(2097152 + 255) / 256, 256, 0, stream>>>((const float4*)x, (ushort4*)xb, 2097152);
    cvt_f32_bf16<<<(262144 + 255) / 256, 256, 0, stream>>>((const float4*)wq, (ushort4*)wqkvb, 262144);
    cvt_f32_bf16<<<(65536 + 255) / 256, 256, 0, stream>>>((const float4*)wk, (ushort4*)(wqkvb + 1048576), 65536);
    cvt_f32_bf16<<<(65536 + 255) / 256, 256, 0, stream>>>((const float4*)wv, (ushort4*)(wqkvb + 1310720), 65536);
    cvt_f32_bf16<<<(262144 + 255) / 256, 256, 0, stream>>>((const float4*)wo, (ushort4*)wob, 262144);

    trig_table<<<256, 256, 0, stream>>>(tbl);

    gemm_bt<<<dim3(64, 12), 256, 0, stream>>>(xb, wqkvb, qkv, 8192, 1536, 1024);

    rope_norm<<<(8192 * 24) / 4, 256, 0, stream>>>(qkv, tbl, qb, kb, vb);

    vtrans<<<dim3(32, 16), 256, 0, stream>>>(vb, vt);

    attn_fwd<<<1024, 256, 0, stream>>>(qb, kb, vt, ybf);

    gemm_bt<<<dim3(64, 8), 256, 0, stream>>>(ybf, wob, out, 8192, 1024, 1024);
}